// Round 5
// baseline (335.312 us; speedup 1.0000x reference)
//
#include <hip/hip_runtime.h>
#include <hip/hip_bf16.h>

#define NPTS  4096
#define BATCH 4
#define KK    16
#define CH    64
#define SURV_CAP 64
#define KWAVES 8

// ---------------------------------------------------------------------------
// Kernel A: exact KNN via pivot + compact + bitonic sort.
// 512 threads = 8 waves = 8 queries per block. All 4096 points of the batch
// are staged ONCE per block into LDS as padded float4 (16B-aligned ->
// single conflict-free ds_read_b128 per point), replacing the per-query
// 12B-stride global scatter that dominated round 4.
// Selection logic unchanged from the round-4 version (verified passing):
// pivot T = 17th smallest of 64 lane-minima (provable superset bound),
// ballot-compact survivors, bitonic sort of (d_bits<<32|j) u64 keys ==
// top_k (dist, index) order. Exact fallback if >64 survivors.
// ---------------------------------------------------------------------------
__global__ __launch_bounds__(512) void knn_kernel(const float* __restrict__ xyz,
                                                  int* __restrict__ knn_idx) {
    __shared__ float4 lx4[NPTS];                       // 64 KB
    __shared__ unsigned long long sbuf[KWAVES][SURV_CAP]; // 4 KB
    const int wave = threadIdx.x >> 6;
    const int lane = threadIdx.x & 63;
    const int q = blockIdx.x * KWAVES + wave;   // 8 queries/block, same batch
    const int b = q >> 12;
    const int i = q & (NPTS - 1);
    const float* xb = xyz + (size_t)b * NPTS * 3;

    // ---- stage xyz -> LDS (AoS4, pad 0) ----
#pragma unroll
    for (int r = 0; r < NPTS / 512; ++r) {
        const int pt = r * 512 + threadIdx.x;
        lx4[pt] = make_float4(xb[pt * 3 + 0], xb[pt * 3 + 1], xb[pt * 3 + 2], 0.f);
    }
    __syncthreads();

    const float qx = lx4[i].x;
    const float qy = lx4[i].y;
    const float qz = lx4[i].z;

    // ---- distances in VGPRs, exact reference arithmetic ----
    float d[64];
    {
#pragma clang fp contract(off)
#pragma unroll
        for (int t = 0; t < 64; ++t) {
            const float4 p = lx4[t * 64 + lane];
            const float dx = p.x - qx;
            const float dy = p.y - qy;
            const float dz = p.z - qz;
            const float sx = dx * dx;
            const float sy = dy * dy;
            const float sz = dz * dz;
            d[t] = (sx + sy) + sz;
        }
    }

    // ---- per-lane min ----
    float m = d[0];
#pragma unroll
    for (int t = 1; t < 64; ++t) m = fminf(m, d[t]);

    // ---- bitonic sort the 64 lane-minima (ascending by lane) ----
#pragma unroll
    for (int k = 2; k <= 64; k <<= 1) {
#pragma unroll
        for (int jj = k >> 1; jj > 0; jj >>= 1) {
            const float p = __shfl_xor(m, jj);
            const bool takeMin = (((lane & jj) == 0) == ((lane & k) == 0));
            const bool pLess = p < m;
            m = (pLess == takeMin) ? p : m;
        }
    }
    const float T = __shfl(m, 16);              // 17th smallest lane-min

    // ---- ballot-compact survivors (d <= T) into per-wave LDS ----
    int base = 0;
#pragma unroll
    for (int t = 0; t < 64; ++t) {
        const bool sv = d[t] <= T;
        const unsigned long long mask = __ballot(sv);
        const int below = __popcll(mask & ((1ull << lane) - 1ull));
        const int slot = base + below;
        if (sv && slot < SURV_CAP) {
            const int j = t * 64 + lane;
            sbuf[wave][slot] =
                ((unsigned long long)__float_as_uint(d[t]) << 32) | (unsigned)j;
        }
        base += __popcll(mask);
    }
    const int total = base;

    if (total <= SURV_CAP) {
        // ---- bitonic sort u64 keys (dist, index) ascending ----
        unsigned long long key = (lane < total) ? sbuf[wave][lane] : ~0ull;
#pragma unroll
        for (int k = 2; k <= 64; k <<= 1) {
#pragma unroll
            for (int jj = k >> 1; jj > 0; jj >>= 1) {
                const unsigned long long p = __shfl_xor(key, jj);
                const bool takeMin = (((lane & jj) == 0) == ((lane & k) == 0));
                const bool pLess = p < key;
                key = (pLess == takeMin) ? p : key;
            }
        }
        if (lane >= 1 && lane <= KK)
            knn_idx[(size_t)q * KK + lane - 1] = (int)(key & 0xffffffffu);
    } else {
        // ---- exact fallback: lexicographic successive-min ----
        float dp = -1.0f; int jp = -1;
        for (int pass = 0; pass < KK + 1; ++pass) {
            float dmin = 3.4e38f; int jmin = 0x7fffffff;
#pragma unroll
            for (int t = 0; t < 64; ++t) {
                const int j = t * 64 + lane;
                const bool valid = (d[t] > dp) || (d[t] == dp && j > jp);
                const bool less =
                    valid && (d[t] < dmin || (d[t] == dmin && j < jmin));
                dmin = less ? d[t] : dmin;
                jmin = less ? j : jmin;
            }
#pragma unroll
            for (int off = 32; off > 0; off >>= 1) {
                const float d2 = __shfl_xor(dmin, off);
                const int   j2 = __shfl_xor(jmin, off);
                if (d2 < dmin || (d2 == dmin && j2 < jmin)) { dmin = d2; jmin = j2; }
            }
            if (pass >= 1 && lane == 0)
                knn_idx[(size_t)q * KK + pass - 1] = jmin;
            dp = dmin; jp = jmin;
        }
    }
}

// ---------------------------------------------------------------------------
// Kernel B: column-per-lane MLP. lane = (p4 = lane>>4, nb = lane&15); each
// lane carries one (point, neighbor) column h[64] through all layers in
// VGPRs. Weights are lane-uniform -> s_load broadcast (SMEM pipe), so the
// math does ZERO LDS traffic (kills the 8.16M bank conflicts / LDS-pipe
// bottleneck of round 4). Layers 2+3 fused, streaming over intermediate
// channel c: dot(w2-row[c], h) -> relu -> scatter-FMA into static acc3[64]
// (w2 row = contiguous s_loads; w3 column = base + c3*256B imm offsets).
// Max over nb = 4x shfl_xor per channel. 4 points/wave, 16/block.
// ---------------------------------------------------------------------------
__global__ __launch_bounds__(256) void mlp_kernel(const float* __restrict__ xyz,
                                                  const int* __restrict__ knn_idx,
                                                  const float* __restrict__ w1,
                                                  const float* __restrict__ w2,
                                                  const float* __restrict__ w3,
                                                  float* __restrict__ out) {
    __shared__ float obuf[CH][17];                    // +1 pad: conflict-free
    const int tid = threadIdx.x;
    const int wave = tid >> 6, lane = tid & 63;
    const int nb = lane & 15, p4 = lane >> 4;
    const int base = blockIdx.x * 16;                 // 16 points per block
    const int b = base >> 12, n0 = base & (NPTS - 1);
    const int n = n0 + wave * 4 + p4;                 // this lane's point
    const float* xb = xyz + (size_t)b * NPTS * 3;

    // ---- gather relative coords (coalesced knn read: addr is tid-linear) --
    const int j = knn_idx[((size_t)b * NPTS + n) * KK + nb];
    const float gx = xb[j * 3 + 0] - xb[n * 3 + 0];
    const float gy = xb[j * 3 + 1] - xb[n * 3 + 1];
    const float gz = xb[j * 3 + 2] - xb[n * 3 + 2];

    // ---- layer 1 (w1 uniform -> s_load) ----
    float h[CH];
#pragma unroll
    for (int c = 0; c < CH; ++c) {
        const float v = w1[c * 3 + 0] * gx + w1[c * 3 + 1] * gy + w1[c * 3 + 2] * gz;
        h[c] = v > 0.f ? v : 0.f;
    }

    // ---- layers 2+3 fused, streaming over intermediate channel c ----
    float acc3[CH];
#pragma unroll
    for (int c3 = 0; c3 < CH; ++c3) acc3[c3] = 0.f;

#pragma unroll 2
    for (int c = 0; c < CH; ++c) {
        const float* w2r = w2 + c * CH;               // contiguous row
        float s0 = 0.f, s1 = 0.f, s2 = 0.f, s3 = 0.f;
#pragma unroll
        for (int cp = 0; cp < CH; cp += 4) {          // 4 chains: hide FMA lat
            s0 += w2r[cp + 0] * h[cp + 0];
            s1 += w2r[cp + 1] * h[cp + 1];
            s2 += w2r[cp + 2] * h[cp + 2];
            s3 += w2r[cp + 3] * h[cp + 3];
        }
        float s = (s0 + s1) + (s2 + s3);
        s = s > 0.f ? s : 0.f;                        // relu (layer 2)
        const float* w3c = w3 + c;                    // column: imm offsets
#pragma unroll
        for (int c3 = 0; c3 < CH; ++c3)
            acc3[c3] += w3c[c3 * CH] * s;             // independent FMAs
    }

    // ---- max over the 16 neighbor lanes, keep 4 channels per lane ----
    float o[4];
#pragma unroll
    for (int c = 0; c < CH; ++c) {
        float v = acc3[c];
#pragma unroll
        for (int off = 1; off < 16; off <<= 1)
            v = fmaxf(v, __shfl_xor(v, off));
        if (nb == (c & 15)) o[c >> 4] = v;            // c>>4 static
    }
#pragma unroll
    for (int g = 0; g < 4; ++g)
        obuf[g * 16 + nb][wave * 4 + p4] = o[g];
    __syncthreads();

    // ---- coalesced output: 4 threads -> 64B contiguous per channel row ----
    {
        const int c = tid >> 2, seg = tid & 3;
        const float4 v = make_float4(obuf[c][seg * 4 + 0], obuf[c][seg * 4 + 1],
                                     obuf[c][seg * 4 + 2], obuf[c][seg * 4 + 3]);
        *(float4*)&out[((size_t)(b * CH + c)) * NPTS + n0 + seg * 4] = v;
    }
}

extern "C" void kernel_launch(void* const* d_in, const int* in_sizes, int n_in,
                              void* d_out, int out_size, void* d_ws, size_t ws_size,
                              hipStream_t stream) {
    (void)in_sizes; (void)n_in; (void)out_size; (void)ws_size;
    const float* xyz = (const float*)d_in[0];
    const float* w1  = (const float*)d_in[1];
    const float* w2  = (const float*)d_in[2];
    const float* w3  = (const float*)d_in[3];
    // d_in[4] is k (always 16 for this problem)
    int*   knn = (int*)d_ws;                 // BATCH*NPTS*KK ints = 1 MiB
    float* out = (float*)d_out;

    knn_kernel<<<BATCH * NPTS / KWAVES, 512, 0, stream>>>(xyz, knn);
    mlp_kernel<<<BATCH * NPTS / 16, 256, 0, stream>>>(xyz, knn, w1, w2, w3, out);
}

// Round 6
// 284.212 us; speedup vs baseline: 1.1798x; 1.1798x over previous
//
#include <hip/hip_runtime.h>
#include <hip/hip_bf16.h>

#define NPTS  4096
#define BATCH 4
#define KK    16
#define CH    64
#define SURV_CAP 64
#define KWAVES 8

// ---------------------------------------------------------------------------
// Kernel A: exact KNN via pivot + compact + bitonic sort (unchanged from the
// round-4/5 version that passed; ~113us, to be diagnosed next round).
// ---------------------------------------------------------------------------
__global__ __launch_bounds__(512) void knn_kernel(const float* __restrict__ xyz,
                                                  int* __restrict__ knn_idx) {
    __shared__ float4 lx4[NPTS];                       // 64 KB
    __shared__ unsigned long long sbuf[KWAVES][SURV_CAP]; // 4 KB
    const int wave = threadIdx.x >> 6;
    const int lane = threadIdx.x & 63;
    const int q = blockIdx.x * KWAVES + wave;   // 8 queries/block, same batch
    const int b = q >> 12;
    const int i = q & (NPTS - 1);
    const float* xb = xyz + (size_t)b * NPTS * 3;

    // ---- stage xyz -> LDS (AoS4, pad 0) ----
#pragma unroll
    for (int r = 0; r < NPTS / 512; ++r) {
        const int pt = r * 512 + threadIdx.x;
        lx4[pt] = make_float4(xb[pt * 3 + 0], xb[pt * 3 + 1], xb[pt * 3 + 2], 0.f);
    }
    __syncthreads();

    const float qx = lx4[i].x;
    const float qy = lx4[i].y;
    const float qz = lx4[i].z;

    // ---- distances in VGPRs, exact reference arithmetic ----
    float d[64];
    {
#pragma clang fp contract(off)
#pragma unroll
        for (int t = 0; t < 64; ++t) {
            const float4 p = lx4[t * 64 + lane];
            const float dx = p.x - qx;
            const float dy = p.y - qy;
            const float dz = p.z - qz;
            const float sx = dx * dx;
            const float sy = dy * dy;
            const float sz = dz * dz;
            d[t] = (sx + sy) + sz;
        }
    }

    // ---- per-lane min ----
    float m = d[0];
#pragma unroll
    for (int t = 1; t < 64; ++t) m = fminf(m, d[t]);

    // ---- bitonic sort the 64 lane-minima (ascending by lane) ----
#pragma unroll
    for (int k = 2; k <= 64; k <<= 1) {
#pragma unroll
        for (int jj = k >> 1; jj > 0; jj >>= 1) {
            const float p = __shfl_xor(m, jj);
            const bool takeMin = (((lane & jj) == 0) == ((lane & k) == 0));
            const bool pLess = p < m;
            m = (pLess == takeMin) ? p : m;
        }
    }
    const float T = __shfl(m, 16);              // 17th smallest lane-min

    // ---- ballot-compact survivors (d <= T) into per-wave LDS ----
    int base = 0;
#pragma unroll
    for (int t = 0; t < 64; ++t) {
        const bool sv = d[t] <= T;
        const unsigned long long mask = __ballot(sv);
        const int below = __popcll(mask & ((1ull << lane) - 1ull));
        const int slot = base + below;
        if (sv && slot < SURV_CAP) {
            const int j = t * 64 + lane;
            sbuf[wave][slot] =
                ((unsigned long long)__float_as_uint(d[t]) << 32) | (unsigned)j;
        }
        base += __popcll(mask);
    }
    const int total = base;

    if (total <= SURV_CAP) {
        // ---- bitonic sort u64 keys (dist, index) ascending ----
        unsigned long long key = (lane < total) ? sbuf[wave][lane] : ~0ull;
#pragma unroll
        for (int k = 2; k <= 64; k <<= 1) {
#pragma unroll
            for (int jj = k >> 1; jj > 0; jj >>= 1) {
                const unsigned long long p = __shfl_xor(key, jj);
                const bool takeMin = (((lane & jj) == 0) == ((lane & k) == 0));
                const bool pLess = p < key;
                key = (pLess == takeMin) ? p : key;
            }
        }
        if (lane >= 1 && lane <= KK)
            knn_idx[(size_t)q * KK + lane - 1] = (int)(key & 0xffffffffu);
    } else {
        // ---- exact fallback: lexicographic successive-min ----
        float dp = -1.0f; int jp = -1;
        for (int pass = 0; pass < KK + 1; ++pass) {
            float dmin = 3.4e38f; int jmin = 0x7fffffff;
#pragma unroll
            for (int t = 0; t < 64; ++t) {
                const int j = t * 64 + lane;
                const bool valid = (d[t] > dp) || (d[t] == dp && j > jp);
                const bool less =
                    valid && (d[t] < dmin || (d[t] == dmin && j < jmin));
                dmin = less ? d[t] : dmin;
                jmin = less ? j : jmin;
            }
#pragma unroll
            for (int off = 32; off > 0; off >>= 1) {
                const float d2 = __shfl_xor(dmin, off);
                const int   j2 = __shfl_xor(jmin, off);
                if (d2 < dmin || (d2 == dmin && j2 < jmin)) { dmin = d2; jmin = j2; }
            }
            if (pass >= 1 && lane == 0)
                knn_idx[(size_t)q * KK + pass - 1] = jmin;
            dp = dmin; jp = jmin;
        }
    }
}

// ---------------------------------------------------------------------------
// Kernel B: column-per-lane MLP, v3.
//   * __launch_bounds__(256, 2): VGPR cap 256 -> h[64]+acc3[64] genuinely in
//     registers (round 5's VGPR=72 proved the allocator demoted them).
//   * Weights staged once per block into LDS; all weight reads in the c-loop
//     are WAVE-UNIFORM ds_read_b128 broadcasts (single address -> no
//     conflicts, no SGPR file pressure, no s_load batching stalls).
//   * W3 staged TRANSPOSED so its per-c column is a contiguous 256B row.
// Per c: 32 LDS broadcast reads (~100 cyc pipe) vs 128 FMA (256 cyc VALU)
// -> VALU-bound. Ideal ~28us.
// ---------------------------------------------------------------------------
__global__ __launch_bounds__(256, 2) void mlp_kernel(const float* __restrict__ xyz,
                                                     const int* __restrict__ knn_idx,
                                                     const float* __restrict__ w1,
                                                     const float* __restrict__ w2,
                                                     const float* __restrict__ w3,
                                                     float* __restrict__ out) {
    __shared__ __align__(16) float w2l[CH][CH];   // w2l[c][cp] = w2[c][cp] (row)
    __shared__ __align__(16) float w3l[CH][CH];   // w3l[c][c3] = w3[c3][c] (col packed)
    __shared__ float obuf[CH][17];                // +1 pad
    const int tid = threadIdx.x;
    const int wave = tid >> 6, lane = tid & 63;
    const int nb = lane & 15, p4 = lane >> 4;
    const int base = blockIdx.x * 16;             // 16 points per block
    const int b = base >> 12, n0 = base & (NPTS - 1);
    const int n = n0 + wave * 4 + p4;             // this lane's point
    const float* xb = xyz + (size_t)b * NPTS * 3;

    // ---- stage weights -> LDS ----
    for (int s = tid; s < CH * CH; s += 256) {
        (&w2l[0][0])[s] = w2[s];                  // coalesced
        const int c = s >> 6, r = s & 63;         // w3l[c][r] = w3[r][c]
        w3l[c][r] = w3[r * CH + c];
    }
    __syncthreads();

    // ---- gather relative coords (coalesced knn read: addr is tid-linear) --
    const int j = knn_idx[((size_t)b * NPTS + n) * KK + nb];
    const float gx = xb[j * 3 + 0] - xb[n * 3 + 0];
    const float gy = xb[j * 3 + 1] - xb[n * 3 + 1];
    const float gz = xb[j * 3 + 2] - xb[n * 3 + 2];

    // ---- layer 1 (w1 uniform -> s_load broadcast) ----
    float h[CH];
#pragma unroll
    for (int c = 0; c < CH; ++c) {
        const float v = w1[c * 3 + 0] * gx + w1[c * 3 + 1] * gy + w1[c * 3 + 2] * gz;
        h[c] = v > 0.f ? v : 0.f;
    }

    // ---- layers 2+3 fused, streaming over intermediate channel c ----
    float acc3[CH];
#pragma unroll
    for (int c3 = 0; c3 < CH; ++c3) acc3[c3] = 0.f;

#pragma unroll 2
    for (int c = 0; c < CH; ++c) {
        // dot(w2 row c, h): 16 uniform b128 broadcasts, 4 FMA chains
        float s0 = 0.f, s1 = 0.f, s2 = 0.f, s3 = 0.f;
#pragma unroll
        for (int i = 0; i < 16; ++i) {
            const float4 w = *(const float4*)&w2l[c][i * 4];
            s0 += w.x * h[i * 4 + 0];
            s1 += w.y * h[i * 4 + 1];
            s2 += w.z * h[i * 4 + 2];
            s3 += w.w * h[i * 4 + 3];
        }
        float s = (s0 + s1) + (s2 + s3);
        s = s > 0.f ? s : 0.f;                    // relu (layer 2)
        // scatter: acc3 += w3 column c (contiguous row of w3l), 64 indep FMAs
#pragma unroll
        for (int i = 0; i < 16; ++i) {
            const float4 w = *(const float4*)&w3l[c][i * 4];
            acc3[i * 4 + 0] += w.x * s;
            acc3[i * 4 + 1] += w.y * s;
            acc3[i * 4 + 2] += w.z * s;
            acc3[i * 4 + 3] += w.w * s;
        }
    }

    // ---- max over the 16 neighbor lanes, keep 4 channels per lane ----
    float o[4];
#pragma unroll
    for (int c = 0; c < CH; ++c) {
        float v = acc3[c];
#pragma unroll
        for (int off = 1; off < 16; off <<= 1)
            v = fmaxf(v, __shfl_xor(v, off));
        if (nb == (c & 15)) o[c >> 4] = v;        // c>>4 static
    }
#pragma unroll
    for (int g = 0; g < 4; ++g)
        obuf[g * 16 + nb][wave * 4 + p4] = o[g];
    __syncthreads();

    // ---- coalesced output: 4 threads -> 64B contiguous per channel row ----
    {
        const int c = tid >> 2, seg = tid & 3;
        const float4 v = make_float4(obuf[c][seg * 4 + 0], obuf[c][seg * 4 + 1],
                                     obuf[c][seg * 4 + 2], obuf[c][seg * 4 + 3]);
        *(float4*)&out[((size_t)(b * CH + c)) * NPTS + n0 + seg * 4] = v;
    }
}

extern "C" void kernel_launch(void* const* d_in, const int* in_sizes, int n_in,
                              void* d_out, int out_size, void* d_ws, size_t ws_size,
                              hipStream_t stream) {
    (void)in_sizes; (void)n_in; (void)out_size; (void)ws_size;
    const float* xyz = (const float*)d_in[0];
    const float* w1  = (const float*)d_in[1];
    const float* w2  = (const float*)d_in[2];
    const float* w3  = (const float*)d_in[3];
    // d_in[4] is k (always 16 for this problem)
    int*   knn = (int*)d_ws;                 // BATCH*NPTS*KK ints = 1 MiB
    float* out = (float*)d_out;

    knn_kernel<<<BATCH * NPTS / KWAVES, 512, 0, stream>>>(xyz, knn);
    mlp_kernel<<<BATCH * NPTS / 16, 256, 0, stream>>>(xyz, knn, w1, w2, w3, out);
}

// Round 7
// 173.593 us; speedup vs baseline: 1.9316x; 1.6372x over previous
//
#include <hip/hip_runtime.h>
#include <hip/hip_bf16.h>

#define NPTS  4096
#define BATCH 4
#define KK    16
#define CH    64
#define SURV_CAP 64
#define KWAVES 8

typedef __attribute__((ext_vector_type(8))) short bf16x8;
typedef __attribute__((ext_vector_type(4))) float f32x4;

// split-bf16: x = hi + lo exactly to ~2^-17 rel. hi = truncate-to-bf16 (drop
// low mantissa), x - hi exact (same exponent), lo = bf16(residual).
__device__ __forceinline__ unsigned short bhi(float x) {
    return (unsigned short)(__float_as_uint(x) >> 16);
}
__device__ __forceinline__ unsigned short blo(float x) {
    const float h = __uint_as_float(__float_as_uint(x) & 0xffff0000u);
    return (unsigned short)(__float_as_uint(x - h) >> 16);
}
__device__ __forceinline__ unsigned pk2(unsigned short a, unsigned short b) {
    return (unsigned)a | ((unsigned)b << 16);
}

// ---------------------------------------------------------------------------
// Kernel A: exact KNN (UNCHANGED from round-4/5/6 passing version).
// ---------------------------------------------------------------------------
__global__ __launch_bounds__(512) void knn_kernel(const float* __restrict__ xyz,
                                                  int* __restrict__ knn_idx) {
    __shared__ float4 lx4[NPTS];                       // 64 KB
    __shared__ unsigned long long sbuf[KWAVES][SURV_CAP];
    const int wave = threadIdx.x >> 6;
    const int lane = threadIdx.x & 63;
    const int q = blockIdx.x * KWAVES + wave;
    const int b = q >> 12;
    const int i = q & (NPTS - 1);
    const float* xb = xyz + (size_t)b * NPTS * 3;

#pragma unroll
    for (int r = 0; r < NPTS / 512; ++r) {
        const int pt = r * 512 + threadIdx.x;
        lx4[pt] = make_float4(xb[pt * 3 + 0], xb[pt * 3 + 1], xb[pt * 3 + 2], 0.f);
    }
    __syncthreads();

    const float qx = lx4[i].x;
    const float qy = lx4[i].y;
    const float qz = lx4[i].z;

    float d[64];
    {
#pragma clang fp contract(off)
#pragma unroll
        for (int t = 0; t < 64; ++t) {
            const float4 p = lx4[t * 64 + lane];
            const float dx = p.x - qx;
            const float dy = p.y - qy;
            const float dz = p.z - qz;
            const float sx = dx * dx;
            const float sy = dy * dy;
            const float sz = dz * dz;
            d[t] = (sx + sy) + sz;
        }
    }

    float m = d[0];
#pragma unroll
    for (int t = 1; t < 64; ++t) m = fminf(m, d[t]);

#pragma unroll
    for (int k = 2; k <= 64; k <<= 1) {
#pragma unroll
        for (int jj = k >> 1; jj > 0; jj >>= 1) {
            const float p = __shfl_xor(m, jj);
            const bool takeMin = (((lane & jj) == 0) == ((lane & k) == 0));
            const bool pLess = p < m;
            m = (pLess == takeMin) ? p : m;
        }
    }
    const float T = __shfl(m, 16);

    int base = 0;
#pragma unroll
    for (int t = 0; t < 64; ++t) {
        const bool sv = d[t] <= T;
        const unsigned long long mask = __ballot(sv);
        const int below = __popcll(mask & ((1ull << lane) - 1ull));
        const int slot = base + below;
        if (sv && slot < SURV_CAP) {
            const int j = t * 64 + lane;
            sbuf[wave][slot] =
                ((unsigned long long)__float_as_uint(d[t]) << 32) | (unsigned)j;
        }
        base += __popcll(mask);
    }
    const int total = base;

    if (total <= SURV_CAP) {
        unsigned long long key = (lane < total) ? sbuf[wave][lane] : ~0ull;
#pragma unroll
        for (int k = 2; k <= 64; k <<= 1) {
#pragma unroll
            for (int jj = k >> 1; jj > 0; jj >>= 1) {
                const unsigned long long p = __shfl_xor(key, jj);
                const bool takeMin = (((lane & jj) == 0) == ((lane & k) == 0));
                const bool pLess = p < key;
                key = (pLess == takeMin) ? p : key;
            }
        }
        if (lane >= 1 && lane <= KK)
            knn_idx[(size_t)q * KK + lane - 1] = (int)(key & 0xffffffffu);
    } else {
        float dp = -1.0f; int jp = -1;
        for (int pass = 0; pass < KK + 1; ++pass) {
            float dmin = 3.4e38f; int jmin = 0x7fffffff;
#pragma unroll
            for (int t = 0; t < 64; ++t) {
                const int j = t * 64 + lane;
                const bool valid = (d[t] > dp) || (d[t] == dp && j > jp);
                const bool less =
                    valid && (d[t] < dmin || (d[t] == dmin && j < jmin));
                dmin = less ? d[t] : dmin;
                jmin = less ? j : jmin;
            }
#pragma unroll
            for (int off = 32; off > 0; off >>= 1) {
                const float d2 = __shfl_xor(dmin, off);
                const int   j2 = __shfl_xor(jmin, off);
                if (d2 < dmin || (d2 == dmin && j2 < jmin)) { dmin = d2; jmin = j2; }
            }
            if (pass >= 1 && lane == 0)
                knn_idx[(size_t)q * KK + pass - 1] = jmin;
            dp = dmin; jp = jmin;
        }
    }
}

// ---------------------------------------------------------------------------
// Kernel B: split-bf16 MFMA MLP.
// Block = 256 thr (4 waves), 8 points; wave = 32 columns (2 points x 16 nb).
// All layers are mfma_f32_16x16x32_bf16 with x = hi+lo split (3 MFMA terms,
// f32 accum -> ~2^-17 rel error). Pipeline per layer: B-frags from per-wave
// colbuf ([col][k] bf16, XOR-swizzled 16B blocks -> <=2-way conflicts),
// A-frags from block-shared swizzled weight LDS, MFMA, relu, split/pack,
// write back to colbuf. Per-wave LDS ops ~120 vs round-6's 2048 (the
// measured LDS-issue bottleneck). Max over nb = shfl_xor{1,2,4,8}.
// Layouts (verified m89/m91): A[row=l&15][k=(l>>4)*8+j], B[k][col=l&15],
// D col=l&15, row=(l>>4)*4+reg.
// ---------------------------------------------------------------------------
__global__ __launch_bounds__(256, 2) void mlp_kernel(const float* __restrict__ xyz,
                                                     const int* __restrict__ knn_idx,
                                                     const float* __restrict__ w1,
                                                     const float* __restrict__ w2,
                                                     const float* __restrict__ w3,
                                                     float* __restrict__ out) {
    __shared__ __align__(16) unsigned short w1h[64 * 32], w1l[64 * 32];
    __shared__ __align__(16) unsigned short w2h[64 * 64], w2l[64 * 64];
    __shared__ __align__(16) unsigned short w3h[64 * 64], w3l[64 * 64];
    __shared__ __align__(16) unsigned short cbh[4][32 * 64], cbl[4][32 * 64];
    __shared__ float obuf[CH][9];

    const int tid = threadIdx.x;
    const int wave = tid >> 6, lane = tid & 63;
    const int lq = lane & 15, lg = lane >> 4;
    const int bx = blockIdx.x;
    const int bb = bx >> 9;
    const int n0 = (bx & 511) * 8;
    const float* xb = xyz + (size_t)bb * NPTS * 3;

    // ---- stage W1 [64][32] (k>2 zeros), swizzle: blk^(r&3) ----
    if (tid < 128) {
        const int r = tid >> 1, kh = (tid & 1) * 16;
#pragma unroll
        for (int kp = 0; kp < 16; kp += 2) {
            const int k = kh + kp;
            const float x0 = (k < 3) ? w1[r * 3 + k] : 0.f;
            const float x1 = (k + 1 < 3) ? w1[r * 3 + k + 1] : 0.f;
            const int byt = r * 64 + (((k >> 3) ^ (r & 3)) << 4) + (k & 7) * 2;
            *(unsigned*)((char*)w1h + byt) = pk2(bhi(x0), bhi(x1));
            *(unsigned*)((char*)w1l + byt) = pk2(blo(x0), blo(x1));
        }
    }
    // ---- stage W2/W3 [64][64], swizzle: blk^(r&7) ----
    {
        const int r = tid >> 2, kb = (tid & 3) * 16;
#pragma unroll
        for (int kp = 0; kp < 16; kp += 2) {
            const int k = kb + kp;
            const float a0 = w2[r * 64 + k], a1 = w2[r * 64 + k + 1];
            const float c0 = w3[r * 64 + k], c1 = w3[r * 64 + k + 1];
            const int byt = r * 128 + (((k >> 3) ^ (r & 7)) << 4) + (k & 7) * 2;
            *(unsigned*)((char*)w2h + byt) = pk2(bhi(a0), bhi(a1));
            *(unsigned*)((char*)w2l + byt) = pk2(blo(a0), blo(a1));
            *(unsigned*)((char*)w3h + byt) = pk2(bhi(c0), bhi(c1));
            *(unsigned*)((char*)w3l + byt) = pk2(blo(c0), blo(c1));
        }
    }
    __syncthreads();

    // ---- gather relative coords: lane (lane&31) owns column (point,nb) ----
    const int col = lane & 31;
    const int n = n0 + wave * 2 + (col >> 4);
    const int j = knn_idx[((size_t)bb * NPTS + n) * KK + (col & 15)];
    const float gx = xb[j * 3 + 0] - xb[n * 3 + 0];
    const float gy = xb[j * 3 + 1] - xb[n * 3 + 1];
    const float gz = xb[j * 3 + 2] - xb[n * 3 + 2];

    unsigned short* const cbH = cbh[wave];
    unsigned short* const cbL = cbl[wave];

    f32x4 acc[4][2];

    // ---- layer 1: B1 frags from g (k=0..2 nonzero, lanes lg==0 only) ----
    bf16x8 b1h[2], b1l[2];
#pragma unroll
    for (int t = 0; t < 2; ++t) {
        const int src = t * 16 + lq;
        const float sx = __shfl(gx, src);
        const float sy = __shfl(gy, src);
        const float sz = __shfl(gz, src);
        bf16x8 h = {}, l = {};
        if (lg == 0) {
            h[0] = (short)bhi(sx); h[1] = (short)bhi(sy); h[2] = (short)bhi(sz);
            l[0] = (short)blo(sx); l[1] = (short)blo(sy); l[2] = (short)blo(sz);
        }
        b1h[t] = h; b1l[t] = l;
    }
#pragma unroll
    for (int m = 0; m < 4; ++m)
#pragma unroll
        for (int t = 0; t < 2; ++t) acc[m][t] = (f32x4){0.f, 0.f, 0.f, 0.f};
#pragma unroll
    for (int m = 0; m < 4; ++m) {
        const int r = m * 16 + lq;
        const int byt = r * 64 + ((lg ^ (r & 3)) << 4);
        const bf16x8 ah = *(const bf16x8*)((const char*)w1h + byt);
        const bf16x8 al = *(const bf16x8*)((const char*)w1l + byt);
#pragma unroll
        for (int t = 0; t < 2; ++t) {
            acc[m][t] = __builtin_amdgcn_mfma_f32_16x16x32_bf16(ah, b1h[t], acc[m][t], 0, 0, 0);
            acc[m][t] = __builtin_amdgcn_mfma_f32_16x16x32_bf16(ah, b1l[t], acc[m][t], 0, 0, 0);
            acc[m][t] = __builtin_amdgcn_mfma_f32_16x16x32_bf16(al, b1h[t], acc[m][t], 0, 0, 0);
        }
    }

    // relu + split + pack acc -> per-wave colbuf [col][k]
    auto spill = [&]() {
#pragma unroll
        for (int m = 0; m < 4; ++m)
#pragma unroll
            for (int t = 0; t < 2; ++t) {
                f32x4 v = acc[m][t];
#pragma unroll
                for (int e = 0; e < 4; ++e) v[e] = fmaxf(v[e], 0.f);
                const int co = t * 16 + lq;
                const int k0 = m * 16 + lg * 4;
                const int byt = co * 128 + (((k0 >> 3) ^ (co & 7)) << 4) + (k0 & 7) * 2;
                uint2 hw, lw;
                hw.x = pk2(bhi(v[0]), bhi(v[1])); hw.y = pk2(bhi(v[2]), bhi(v[3]));
                lw.x = pk2(blo(v[0]), blo(v[1])); lw.y = pk2(blo(v[2]), blo(v[3]));
                *(uint2*)((char*)cbH + byt) = hw;
                *(uint2*)((char*)cbL + byt) = lw;
            }
    };

    // one 64x64 split-bf16 GEMM layer from colbuf
    auto gemm = [&](const unsigned short* WH, const unsigned short* WL) {
        bf16x8 bh[2][2], bl[2][2];
#pragma unroll
        for (int s = 0; s < 2; ++s)
#pragma unroll
            for (int t = 0; t < 2; ++t) {
                const int co = t * 16 + lq;
                const int byt = co * 128 + (((s * 4 + lg) ^ (co & 7)) << 4);
                bh[s][t] = *(const bf16x8*)((const char*)cbH + byt);
                bl[s][t] = *(const bf16x8*)((const char*)cbL + byt);
            }
#pragma unroll
        for (int m = 0; m < 4; ++m)
#pragma unroll
            for (int t = 0; t < 2; ++t) acc[m][t] = (f32x4){0.f, 0.f, 0.f, 0.f};
#pragma unroll
        for (int m = 0; m < 4; ++m) {
            const int r = m * 16 + lq;
#pragma unroll
            for (int s = 0; s < 2; ++s) {
                const int byt = r * 128 + (((s * 4 + lg) ^ (r & 7)) << 4);
                const bf16x8 ah = *(const bf16x8*)((const char*)WH + byt);
                const bf16x8 al = *(const bf16x8*)((const char*)WL + byt);
#pragma unroll
                for (int t = 0; t < 2; ++t) {
                    acc[m][t] = __builtin_amdgcn_mfma_f32_16x16x32_bf16(ah, bh[s][t], acc[m][t], 0, 0, 0);
                    acc[m][t] = __builtin_amdgcn_mfma_f32_16x16x32_bf16(ah, bl[s][t], acc[m][t], 0, 0, 0);
                    acc[m][t] = __builtin_amdgcn_mfma_f32_16x16x32_bf16(al, bh[s][t], acc[m][t], 0, 0, 0);
                }
            }
        }
    };

    spill();            // relu(h1) -> colbuf
    gemm(w2h, w2l);     // acc = W2 h1
    spill();            // relu(h2) -> colbuf (reads in gemm precede, in-order DS)
    gemm(w3h, w3l);     // acc = W3 h2 (no relu)

    // ---- max over 16 neighbor lanes; rows -> obuf ----
#pragma unroll
    for (int m = 0; m < 4; ++m)
#pragma unroll
        for (int t = 0; t < 2; ++t)
#pragma unroll
            for (int e = 0; e < 4; ++e) {
                float v = acc[m][t][e];
                v = fmaxf(v, __shfl_xor(v, 1));
                v = fmaxf(v, __shfl_xor(v, 2));
                v = fmaxf(v, __shfl_xor(v, 4));
                v = fmaxf(v, __shfl_xor(v, 8));
                if (lq == 0) obuf[m * 16 + lg * 4 + e][wave * 2 + t] = v;
            }
    __syncthreads();

    // ---- coalesced store: out[(b*64+c)*4096 + n0 + p], 8 pts/block ----
    {
        const int c = tid >> 2, qq = tid & 3;
        *(float2*)&out[((size_t)(bb * CH + c)) * NPTS + n0 + qq * 2] =
            make_float2(obuf[c][qq * 2], obuf[c][qq * 2 + 1]);
    }
}

extern "C" void kernel_launch(void* const* d_in, const int* in_sizes, int n_in,
                              void* d_out, int out_size, void* d_ws, size_t ws_size,
                              hipStream_t stream) {
    (void)in_sizes; (void)n_in; (void)out_size; (void)ws_size;
    const float* xyz = (const float*)d_in[0];
    const float* w1  = (const float*)d_in[1];
    const float* w2  = (const float*)d_in[2];
    const float* w3  = (const float*)d_in[3];
    int*   knn = (int*)d_ws;                 // BATCH*NPTS*KK ints = 1 MiB
    float* out = (float*)d_out;

    knn_kernel<<<BATCH * NPTS / KWAVES, 512, 0, stream>>>(xyz, knn);
    mlp_kernel<<<BATCH * NPTS / 8, 256, 0, stream>>>(xyz, knn, w1, w2, w3, out);
}

// Round 9
// 164.447 us; speedup vs baseline: 2.0390x; 1.0556x over previous
//
#include <hip/hip_runtime.h>
#include <hip/hip_bf16.h>

#define NPTS  4096
#define BATCH 4
#define KK    16
#define CH    64
#define SURV_CAP 64

typedef __attribute__((ext_vector_type(8))) short bf16x8;
typedef __attribute__((ext_vector_type(4))) float f32x4;

__device__ __forceinline__ unsigned short bhi(float x) {
    return (unsigned short)(__float_as_uint(x) >> 16);
}
__device__ __forceinline__ unsigned short blo(float x) {
    const float h = __uint_as_float(__float_as_uint(x) & 0xffff0000u);
    return (unsigned short)(__float_as_uint(x - h) >> 16);
}
__device__ __forceinline__ unsigned pk2(unsigned short a, unsigned short b) {
    return (unsigned)a | ((unsigned)b << 16);
}

// Reference-rounded squared distance: (mul,mul,mul,add,add), NO contraction —
// pragma opens the function's compound statement (file-scope-legal form).
__device__ __forceinline__ float ref_dist(float4 p, float qx, float qy, float qz) {
#pragma clang fp contract(off)
    const float dx = p.x - qx, dy = p.y - qy, dz = p.z - qz;
    const float sx = dx * dx, sy = dy * dy, sz = dz * dz;
    return (sx + sy) + sz;
}

// ---------------------------------------------------------------------------
// Kernel A: exact KNN, 2 queries per wave.
// Approx rank key s~ = |p|^2 - 2 p.q (fma form, error <= ~6e-5) drives the
// pivot (17th smallest of 64 lane-minima, margin 1e-3 -> provable superset
// of the true top-17 by the reference's f32 key). Survivor INDICES are
// compacted; exact reference-rounded distances (ref_dist) are recomputed for
// survivors only, then a dual-interleaved u64 bitonic sort of (d_bits<<32|j)
// reproduces top_k's (dist, index) order exactly. Each staged point (one
// ds_read_b128) serves both queries.
// ---------------------------------------------------------------------------
__global__ __launch_bounds__(512, 2) void knn_kernel(const float* __restrict__ xyz,
                                                     int* __restrict__ knn_idx) {
    __shared__ float4 lx4[NPTS];                    // 64 KB; w = |p|^2 (approx only)
    __shared__ int sidx[8][2][SURV_CAP];            // 4 KB survivor indices
    const int wave = threadIdx.x >> 6;
    const int lane = threadIdx.x & 63;
    const int q0 = blockIdx.x * 16 + wave * 2;      // queries q0, q0+1 (same batch)
    const int b = q0 >> 12;
    const int iA = q0 & (NPTS - 1), iB = iA + 1;
    const float* xb = xyz + (size_t)b * NPTS * 3;

    // ---- stage xyz (+|p|^2) -> LDS ----
#pragma unroll
    for (int r = 0; r < NPTS / 512; ++r) {
        const int pt = r * 512 + threadIdx.x;
        const float x = xb[pt * 3 + 0];
        const float y = xb[pt * 3 + 1];
        const float z = xb[pt * 3 + 2];
        lx4[pt] = make_float4(x, y, z, fmaf(x, x, fmaf(y, y, z * z)));
    }
    __syncthreads();

    const float4 qa = lx4[iA], qb = lx4[iB];
    const float aAx = -2.f * qa.x, aAy = -2.f * qa.y, aAz = -2.f * qa.z;
    const float aBx = -2.f * qb.x, aBy = -2.f * qb.y, aBz = -2.f * qb.z;

    // ---- approx keys for both queries; per-lane mins ----
    float dA[64], dB[64];
    float mA = 3.4e38f, mB = 3.4e38f;
#pragma unroll
    for (int t = 0; t < 64; ++t) {
        const float4 p = lx4[t * 64 + lane];
        const float sA = fmaf(p.z, aAz, fmaf(p.y, aAy, fmaf(p.x, aAx, p.w)));
        const float sB = fmaf(p.z, aBz, fmaf(p.y, aBy, fmaf(p.x, aBx, p.w)));
        dA[t] = sA; dB[t] = sB;
        mA = fminf(mA, sA); mB = fminf(mB, sB);
    }

    // ---- dual bitonic sort of lane minima (interleaved chains) ----
#pragma unroll
    for (int k = 2; k <= 64; k <<= 1) {
#pragma unroll
        for (int jj = k >> 1; jj > 0; jj >>= 1) {
            const float pA = __shfl_xor(mA, jj);
            const float pB = __shfl_xor(mB, jj);
            const bool tm = (((lane & jj) == 0) == ((lane & k) == 0));
            mA = ((pA < mA) == tm) ? pA : mA;
            mB = ((pB < mB) == tm) ? pB : mB;
        }
    }
    // 17th smallest lane-min + margin (covers approx-vs-exact rank error)
    const float TA = __shfl(mA, 16) + 1e-3f;
    const float TB = __shfl(mB, 16) + 1e-3f;

    // ---- ballot-compact survivor indices for both queries ----
    int baseA = 0, baseB = 0;
#pragma unroll
    for (int t = 0; t < 64; ++t) {
        {
            const bool sv = dA[t] <= TA;
            const unsigned long long mk = __ballot(sv);
            const int slot = baseA + __popcll(mk & ((1ull << lane) - 1ull));
            if (sv && slot < SURV_CAP) sidx[wave][0][slot] = t * 64 + lane;
            baseA += __popcll(mk);
        }
        {
            const bool sv = dB[t] <= TB;
            const unsigned long long mk = __ballot(sv);
            const int slot = baseB + __popcll(mk & ((1ull << lane) - 1ull));
            if (sv && slot < SURV_CAP) sidx[wave][1][slot] = t * 64 + lane;
            baseB += __popcll(mk);
        }
    }

    // ---- exact refine (reference rounding) for survivors ----
    unsigned long long keyA = ~0ull, keyB = ~0ull;
    if (lane < baseA && baseA <= SURV_CAP) {
        const int j = sidx[wave][0][lane];
        const float d = ref_dist(lx4[j], qa.x, qa.y, qa.z);
        keyA = ((unsigned long long)__float_as_uint(d) << 32) | (unsigned)j;
    }
    if (lane < baseB && baseB <= SURV_CAP) {
        const int j = sidx[wave][1][lane];
        const float d = ref_dist(lx4[j], qb.x, qb.y, qb.z);
        keyB = ((unsigned long long)__float_as_uint(d) << 32) | (unsigned)j;
    }

    // ---- dual u64 bitonic sort == top_k (dist, index) order ----
#pragma unroll
    for (int k = 2; k <= 64; k <<= 1) {
#pragma unroll
        for (int jj = k >> 1; jj > 0; jj >>= 1) {
            const unsigned long long pA = __shfl_xor(keyA, jj);
            const unsigned long long pB = __shfl_xor(keyB, jj);
            const bool tm = (((lane & jj) == 0) == ((lane & k) == 0));
            keyA = ((pA < keyA) == tm) ? pA : keyA;
            keyB = ((pB < keyB) == tm) ? pB : keyB;
        }
    }

    // ---- exact fallback (correctness insurance; never runs on real data) --
    auto fallback = [&](int q, float qx, float qy, float qz) {
        float dp = -1.0f; int jp = -1;
        for (int pass = 0; pass < KK + 1; ++pass) {
            float dmin = 3.4e38f; int jmin = 0x7fffffff;
            for (int t = 0; t < 64; ++t) {
                const int j = t * 64 + lane;
                const float d = ref_dist(lx4[j], qx, qy, qz);
                const bool valid = (d > dp) || (d == dp && j > jp);
                const bool less = valid && (d < dmin || (d == dmin && j < jmin));
                dmin = less ? d : dmin;
                jmin = less ? j : jmin;
            }
#pragma unroll
            for (int off = 32; off > 0; off >>= 1) {
                const float d2 = __shfl_xor(dmin, off);
                const int   j2 = __shfl_xor(jmin, off);
                if (d2 < dmin || (d2 == dmin && j2 < jmin)) { dmin = d2; jmin = j2; }
            }
            if (pass >= 1 && lane == 0) knn_idx[(size_t)q * KK + pass - 1] = jmin;
            dp = dmin; jp = jmin;
        }
    };

    if (baseA <= SURV_CAP) {
        if (lane >= 1 && lane <= KK)
            knn_idx[(size_t)q0 * KK + lane - 1] = (int)(keyA & 0xffffffffu);
    } else fallback(q0, qa.x, qa.y, qa.z);
    if (baseB <= SURV_CAP) {
        if (lane >= 1 && lane <= KK)
            knn_idx[(size_t)(q0 + 1) * KK + lane - 1] = (int)(keyB & 0xffffffffu);
    } else fallback(q0 + 1, qb.x, qb.y, qb.z);
}

// ---------------------------------------------------------------------------
// Kernel B: split-bf16 MFMA MLP with group loop.
// Identical inner pipeline to the verified round-7 kernel; each block now
// loops over 8 groups of 8 points, amortizing the weight stage/split 8x.
// ---------------------------------------------------------------------------
__global__ __launch_bounds__(256, 2) void mlp_kernel(const float* __restrict__ xyz,
                                                     const int* __restrict__ knn_idx,
                                                     const float* __restrict__ w1,
                                                     const float* __restrict__ w2,
                                                     const float* __restrict__ w3,
                                                     float* __restrict__ out) {
    __shared__ __align__(16) unsigned short w1h[64 * 32], w1l[64 * 32];
    __shared__ __align__(16) unsigned short w2h[64 * 64], w2l[64 * 64];
    __shared__ __align__(16) unsigned short w3h[64 * 64], w3l[64 * 64];
    __shared__ __align__(16) unsigned short cbh[4][32 * 64], cbl[4][32 * 64];
    __shared__ float obuf[CH][9];

    const int tid = threadIdx.x;
    const int wave = tid >> 6, lane = tid & 63;
    const int lq = lane & 15, lg = lane >> 4;
    const int bx = blockIdx.x;
    const int bb = bx >> 6;                        // 64 blocks per batch
    const int nbase = (bx & 63) * 64;              // 64 points per block
    const float* xb = xyz + (size_t)bb * NPTS * 3;

    // ---- stage W1 [64][32] (k>2 zeros), swizzle blk^(r&3) ----
    if (tid < 128) {
        const int r = tid >> 1, kh = (tid & 1) * 16;
#pragma unroll
        for (int kp = 0; kp < 16; kp += 2) {
            const int k = kh + kp;
            const float x0 = (k < 3) ? w1[r * 3 + k] : 0.f;
            const float x1 = (k + 1 < 3) ? w1[r * 3 + k + 1] : 0.f;
            const int byt = r * 64 + (((k >> 3) ^ (r & 3)) << 4) + (k & 7) * 2;
            *(unsigned*)((char*)w1h + byt) = pk2(bhi(x0), bhi(x1));
            *(unsigned*)((char*)w1l + byt) = pk2(blo(x0), blo(x1));
        }
    }
    // ---- stage W2/W3 [64][64], swizzle blk^(r&7) ----
    {
        const int r = tid >> 2, kb = (tid & 3) * 16;
#pragma unroll
        for (int kp = 0; kp < 16; kp += 2) {
            const int k = kb + kp;
            const float a0 = w2[r * 64 + k], a1 = w2[r * 64 + k + 1];
            const float c0 = w3[r * 64 + k], c1 = w3[r * 64 + k + 1];
            const int byt = r * 128 + (((k >> 3) ^ (r & 7)) << 4) + (k & 7) * 2;
            *(unsigned*)((char*)w2h + byt) = pk2(bhi(a0), bhi(a1));
            *(unsigned*)((char*)w2l + byt) = pk2(blo(a0), blo(a1));
            *(unsigned*)((char*)w3h + byt) = pk2(bhi(c0), bhi(c1));
            *(unsigned*)((char*)w3l + byt) = pk2(blo(c0), blo(c1));
        }
    }
    __syncthreads();

    unsigned short* const cbH = cbh[wave];
    unsigned short* const cbL = cbl[wave];
    const int col = lane & 31;

    for (int g = 0; g < 8; ++g) {
        const int n0 = nbase + g * 8;

        // ---- gather relative coords: lane col owns column (point, nb) ----
        const int n = n0 + wave * 2 + (col >> 4);
        const int j = knn_idx[((size_t)bb * NPTS + n) * KK + (col & 15)];
        const float gx = xb[j * 3 + 0] - xb[n * 3 + 0];
        const float gy = xb[j * 3 + 1] - xb[n * 3 + 1];
        const float gz = xb[j * 3 + 2] - xb[n * 3 + 2];

        f32x4 acc[4][2];

        // ---- layer 1 ----
        bf16x8 b1h[2], b1l[2];
#pragma unroll
        for (int t = 0; t < 2; ++t) {
            const int src = t * 16 + lq;
            const float sx = __shfl(gx, src);
            const float sy = __shfl(gy, src);
            const float sz = __shfl(gz, src);
            bf16x8 h = {}, l = {};
            if (lg == 0) {
                h[0] = (short)bhi(sx); h[1] = (short)bhi(sy); h[2] = (short)bhi(sz);
                l[0] = (short)blo(sx); l[1] = (short)blo(sy); l[2] = (short)blo(sz);
            }
            b1h[t] = h; b1l[t] = l;
        }
#pragma unroll
        for (int m = 0; m < 4; ++m)
#pragma unroll
            for (int t = 0; t < 2; ++t) acc[m][t] = (f32x4){0.f, 0.f, 0.f, 0.f};
#pragma unroll
        for (int m = 0; m < 4; ++m) {
            const int r = m * 16 + lq;
            const int byt = r * 64 + ((lg ^ (r & 3)) << 4);
            const bf16x8 ah = *(const bf16x8*)((const char*)w1h + byt);
            const bf16x8 al = *(const bf16x8*)((const char*)w1l + byt);
#pragma unroll
            for (int t = 0; t < 2; ++t) {
                acc[m][t] = __builtin_amdgcn_mfma_f32_16x16x32_bf16(ah, b1h[t], acc[m][t], 0, 0, 0);
                acc[m][t] = __builtin_amdgcn_mfma_f32_16x16x32_bf16(ah, b1l[t], acc[m][t], 0, 0, 0);
                acc[m][t] = __builtin_amdgcn_mfma_f32_16x16x32_bf16(al, b1h[t], acc[m][t], 0, 0, 0);
            }
        }

        auto spill = [&]() {
#pragma unroll
            for (int m = 0; m < 4; ++m)
#pragma unroll
                for (int t = 0; t < 2; ++t) {
                    f32x4 v = acc[m][t];
#pragma unroll
                    for (int e = 0; e < 4; ++e) v[e] = fmaxf(v[e], 0.f);
                    const int co = t * 16 + lq;
                    const int k0 = m * 16 + lg * 4;
                    const int byt = co * 128 + (((k0 >> 3) ^ (co & 7)) << 4) + (k0 & 7) * 2;
                    uint2 hw, lw;
                    hw.x = pk2(bhi(v[0]), bhi(v[1])); hw.y = pk2(bhi(v[2]), bhi(v[3]));
                    lw.x = pk2(blo(v[0]), blo(v[1])); lw.y = pk2(blo(v[2]), blo(v[3]));
                    *(uint2*)((char*)cbH + byt) = hw;
                    *(uint2*)((char*)cbL + byt) = lw;
                }
        };

        auto gemm = [&](const unsigned short* WH, const unsigned short* WL) {
            bf16x8 bh[2][2], bl[2][2];
#pragma unroll
            for (int s = 0; s < 2; ++s)
#pragma unroll
                for (int t = 0; t < 2; ++t) {
                    const int co = t * 16 + lq;
                    const int byt = co * 128 + (((s * 4 + lg) ^ (co & 7)) << 4);
                    bh[s][t] = *(const bf16x8*)((const char*)cbH + byt);
                    bl[s][t] = *(const bf16x8*)((const char*)cbL + byt);
                }
#pragma unroll
            for (int m = 0; m < 4; ++m)
#pragma unroll
                for (int t = 0; t < 2; ++t) acc[m][t] = (f32x4){0.f, 0.f, 0.f, 0.f};
#pragma unroll
            for (int m = 0; m < 4; ++m) {
                const int r = m * 16 + lq;
#pragma unroll
                for (int s = 0; s < 2; ++s) {
                    const int byt = r * 128 + (((s * 4 + lg) ^ (r & 7)) << 4);
                    const bf16x8 ah = *(const bf16x8*)((const char*)WH + byt);
                    const bf16x8 al = *(const bf16x8*)((const char*)WL + byt);
#pragma unroll
                    for (int t = 0; t < 2; ++t) {
                        acc[m][t] = __builtin_amdgcn_mfma_f32_16x16x32_bf16(ah, bh[s][t], acc[m][t], 0, 0, 0);
                        acc[m][t] = __builtin_amdgcn_mfma_f32_16x16x32_bf16(ah, bl[s][t], acc[m][t], 0, 0, 0);
                        acc[m][t] = __builtin_amdgcn_mfma_f32_16x16x32_bf16(al, bh[s][t], acc[m][t], 0, 0, 0);
                    }
                }
            }
        };

        spill();
        gemm(w2h, w2l);
        spill();
        gemm(w3h, w3l);

        // ---- max over 16 neighbor lanes; rows -> obuf ----
#pragma unroll
        for (int m = 0; m < 4; ++m)
#pragma unroll
            for (int t = 0; t < 2; ++t)
#pragma unroll
                for (int e = 0; e < 4; ++e) {
                    float v = acc[m][t][e];
                    v = fmaxf(v, __shfl_xor(v, 1));
                    v = fmaxf(v, __shfl_xor(v, 2));
                    v = fmaxf(v, __shfl_xor(v, 4));
                    v = fmaxf(v, __shfl_xor(v, 8));
                    if (lq == 0) obuf[m * 16 + lg * 4 + e][wave * 2 + t] = v;
                }
        __syncthreads();

        // ---- coalesced store for this group ----
        {
            const int c = tid >> 2, qq = tid & 3;
            *(float2*)&out[((size_t)(bb * CH + c)) * NPTS + n0 + qq * 2] =
                make_float2(obuf[c][qq * 2], obuf[c][qq * 2 + 1]);
        }
        __syncthreads();   // protect obuf before next group's writes
    }
}

extern "C" void kernel_launch(void* const* d_in, const int* in_sizes, int n_in,
                              void* d_out, int out_size, void* d_ws, size_t ws_size,
                              hipStream_t stream) {
    (void)in_sizes; (void)n_in; (void)out_size; (void)ws_size;
    const float* xyz = (const float*)d_in[0];
    const float* w1  = (const float*)d_in[1];
    const float* w2  = (const float*)d_in[2];
    const float* w3  = (const float*)d_in[3];
    int*   knn = (int*)d_ws;                 // BATCH*NPTS*KK ints = 1 MiB
    float* out = (float*)d_out;

    knn_kernel<<<BATCH * NPTS / 16, 512, 0, stream>>>(xyz, knn);
    mlp_kernel<<<BATCH * NPTS / 64, 256, 0, stream>>>(xyz, knn, w1, w2, w3, out);
}

// Round 10
// 124.331 us; speedup vs baseline: 2.6969x; 1.3227x over previous
//
#include <hip/hip_runtime.h>
#include <hip/hip_bf16.h>

#define NPTS  4096
#define BATCH 4
#define KK    16
#define CH    64
#define SURV_CAP 64

typedef __attribute__((ext_vector_type(8))) short bf16x8;
typedef __attribute__((ext_vector_type(4))) float f32x4;

__device__ __forceinline__ unsigned short bhi(float x) {
    return (unsigned short)(__float_as_uint(x) >> 16);
}
__device__ __forceinline__ unsigned short blo(float x) {
    const float h = __uint_as_float(__float_as_uint(x) & 0xffff0000u);
    return (unsigned short)(__float_as_uint(x - h) >> 16);
}
__device__ __forceinline__ unsigned pk2(unsigned short a, unsigned short b) {
    return (unsigned)a | ((unsigned)b << 16);
}

// Reference-rounded squared distance: (mul,mul,mul,add,add), NO contraction.
__device__ __forceinline__ float ref_dist(float4 p, float qx, float qy, float qz) {
#pragma clang fp contract(off)
    const float dx = p.x - qx, dy = p.y - qy, dz = p.z - qz;
    const float sx = dx * dx, sy = dy * dy, sz = dz * dz;
    return (sx + sy) + sz;
}

// ---------------------------------------------------------------------------
// Kernel A: exact KNN, 2 queries per wave (UNCHANGED from round-9 passing
// version).
// ---------------------------------------------------------------------------
__global__ __launch_bounds__(512, 2) void knn_kernel(const float* __restrict__ xyz,
                                                     int* __restrict__ knn_idx) {
    __shared__ float4 lx4[NPTS];                    // 64 KB; w = |p|^2 (approx only)
    __shared__ int sidx[8][2][SURV_CAP];            // 4 KB survivor indices
    const int wave = threadIdx.x >> 6;
    const int lane = threadIdx.x & 63;
    const int q0 = blockIdx.x * 16 + wave * 2;      // queries q0, q0+1 (same batch)
    const int b = q0 >> 12;
    const int iA = q0 & (NPTS - 1), iB = iA + 1;
    const float* xb = xyz + (size_t)b * NPTS * 3;

#pragma unroll
    for (int r = 0; r < NPTS / 512; ++r) {
        const int pt = r * 512 + threadIdx.x;
        const float x = xb[pt * 3 + 0];
        const float y = xb[pt * 3 + 1];
        const float z = xb[pt * 3 + 2];
        lx4[pt] = make_float4(x, y, z, fmaf(x, x, fmaf(y, y, z * z)));
    }
    __syncthreads();

    const float4 qa = lx4[iA], qb = lx4[iB];
    const float aAx = -2.f * qa.x, aAy = -2.f * qa.y, aAz = -2.f * qa.z;
    const float aBx = -2.f * qb.x, aBy = -2.f * qb.y, aBz = -2.f * qb.z;

    float dA[64], dB[64];
    float mA = 3.4e38f, mB = 3.4e38f;
#pragma unroll
    for (int t = 0; t < 64; ++t) {
        const float4 p = lx4[t * 64 + lane];
        const float sA = fmaf(p.z, aAz, fmaf(p.y, aAy, fmaf(p.x, aAx, p.w)));
        const float sB = fmaf(p.z, aBz, fmaf(p.y, aBy, fmaf(p.x, aBx, p.w)));
        dA[t] = sA; dB[t] = sB;
        mA = fminf(mA, sA); mB = fminf(mB, sB);
    }

#pragma unroll
    for (int k = 2; k <= 64; k <<= 1) {
#pragma unroll
        for (int jj = k >> 1; jj > 0; jj >>= 1) {
            const float pA = __shfl_xor(mA, jj);
            const float pB = __shfl_xor(mB, jj);
            const bool tm = (((lane & jj) == 0) == ((lane & k) == 0));
            mA = ((pA < mA) == tm) ? pA : mA;
            mB = ((pB < mB) == tm) ? pB : mB;
        }
    }
    const float TA = __shfl(mA, 16) + 1e-3f;
    const float TB = __shfl(mB, 16) + 1e-3f;

    int baseA = 0, baseB = 0;
#pragma unroll
    for (int t = 0; t < 64; ++t) {
        {
            const bool sv = dA[t] <= TA;
            const unsigned long long mk = __ballot(sv);
            const int slot = baseA + __popcll(mk & ((1ull << lane) - 1ull));
            if (sv && slot < SURV_CAP) sidx[wave][0][slot] = t * 64 + lane;
            baseA += __popcll(mk);
        }
        {
            const bool sv = dB[t] <= TB;
            const unsigned long long mk = __ballot(sv);
            const int slot = baseB + __popcll(mk & ((1ull << lane) - 1ull));
            if (sv && slot < SURV_CAP) sidx[wave][1][slot] = t * 64 + lane;
            baseB += __popcll(mk);
        }
    }

    unsigned long long keyA = ~0ull, keyB = ~0ull;
    if (lane < baseA && baseA <= SURV_CAP) {
        const int j = sidx[wave][0][lane];
        const float d = ref_dist(lx4[j], qa.x, qa.y, qa.z);
        keyA = ((unsigned long long)__float_as_uint(d) << 32) | (unsigned)j;
    }
    if (lane < baseB && baseB <= SURV_CAP) {
        const int j = sidx[wave][1][lane];
        const float d = ref_dist(lx4[j], qb.x, qb.y, qb.z);
        keyB = ((unsigned long long)__float_as_uint(d) << 32) | (unsigned)j;
    }

#pragma unroll
    for (int k = 2; k <= 64; k <<= 1) {
#pragma unroll
        for (int jj = k >> 1; jj > 0; jj >>= 1) {
            const unsigned long long pA = __shfl_xor(keyA, jj);
            const unsigned long long pB = __shfl_xor(keyB, jj);
            const bool tm = (((lane & jj) == 0) == ((lane & k) == 0));
            keyA = ((pA < keyA) == tm) ? pA : keyA;
            keyB = ((pB < keyB) == tm) ? pB : keyB;
        }
    }

    auto fallback = [&](int q, float qx, float qy, float qz) {
        float dp = -1.0f; int jp = -1;
        for (int pass = 0; pass < KK + 1; ++pass) {
            float dmin = 3.4e38f; int jmin = 0x7fffffff;
            for (int t = 0; t < 64; ++t) {
                const int j = t * 64 + lane;
                const float d = ref_dist(lx4[j], qx, qy, qz);
                const bool valid = (d > dp) || (d == dp && j > jp);
                const bool less = valid && (d < dmin || (d == dmin && j < jmin));
                dmin = less ? d : dmin;
                jmin = less ? j : jmin;
            }
#pragma unroll
            for (int off = 32; off > 0; off >>= 1) {
                const float d2 = __shfl_xor(dmin, off);
                const int   j2 = __shfl_xor(jmin, off);
                if (d2 < dmin || (d2 == dmin && j2 < jmin)) { dmin = d2; jmin = j2; }
            }
            if (pass >= 1 && lane == 0) knn_idx[(size_t)q * KK + pass - 1] = jmin;
            dp = dmin; jp = jmin;
        }
    };

    if (baseA <= SURV_CAP) {
        if (lane >= 1 && lane <= KK)
            knn_idx[(size_t)q0 * KK + lane - 1] = (int)(keyA & 0xffffffffu);
    } else fallback(q0, qa.x, qa.y, qa.z);
    if (baseB <= SURV_CAP) {
        if (lane >= 1 && lane <= KK)
            knn_idx[(size_t)(q0 + 1) * KK + lane - 1] = (int)(keyB & 0xffffffffu);
    } else fallback(q0 + 1, qb.x, qb.y, qb.z);
}

// ---------------------------------------------------------------------------
// Kernel B v5: split-bf16 MFMA MLP, short-chain edition.
//  * 512 blocks (32 pts, 4 groups) -> 2 blocks/CU -> 2 waves/SIMD TLP.
//  * Layer 1 computed per-lane in VALU straight into layer-2 B-frag regs
//    (w1 rows preloaded to registers; g broadcast via 3 shfl) — removes
//    24 MFMA + one LDS round-trip + 8KB staging from the serial chain.
//  * Layer 3 TRANSPOSED: mfma(A=h2frag, B=w3frag) — A/B frag lane-maps are
//    symmetric (m89/m91), colbuf read + w3 staging byte-identical to the
//    verified r9 kernel. D rows = neighbors -> max = 3 v_max + 2 shfl
//    (replaces 128 LDS-pipe shfls).
//  * All 4 gathers prefetched before the group loop; obuf flushed once.
// ---------------------------------------------------------------------------
__global__ __launch_bounds__(256, 2) void mlp_kernel(const float* __restrict__ xyz,
                                                     const int* __restrict__ knn_idx,
                                                     const float* __restrict__ w1,
                                                     const float* __restrict__ w2,
                                                     const float* __restrict__ w3,
                                                     float* __restrict__ out) {
    __shared__ __align__(16) unsigned short w2h[64 * 64], w2l[64 * 64];
    __shared__ __align__(16) unsigned short w3h[64 * 64], w3l[64 * 64];
    __shared__ __align__(16) unsigned short cbh[4][32 * 64], cbl[4][32 * 64];
    __shared__ __align__(16) float obuf[CH][36];   // stride 36: 16B-aligned rows

    const int tid = threadIdx.x;
    const int wave = tid >> 6, lane = tid & 63;
    const int lq = lane & 15, lg = lane >> 4;
    const int bx = blockIdx.x;
    const int bb = bx >> 7;                        // 128 blocks per batch
    const int nbase = (bx & 127) * 32;             // 32 points per block
    const float* xb = xyz + (size_t)bb * NPTS * 3;

    // ---- stage W2/W3 [64 rows][64 k] hi/lo, swizzle blk^(r&7) ----
    {
        const int r = tid >> 2, kb = (tid & 3) * 16;
#pragma unroll
        for (int kp = 0; kp < 16; kp += 2) {
            const int k = kb + kp;
            const float a0 = w2[r * 64 + k], a1 = w2[r * 64 + k + 1];
            const float c0 = w3[r * 64 + k], c1 = w3[r * 64 + k + 1];
            const int byt = r * 128 + (((k >> 3) ^ (r & 7)) << 4) + (k & 7) * 2;
            *(unsigned*)((char*)w2h + byt) = pk2(bhi(a0), bhi(a1));
            *(unsigned*)((char*)w2l + byt) = pk2(blo(a0), blo(a1));
            *(unsigned*)((char*)w3h + byt) = pk2(bhi(c0), bhi(c1));
            *(unsigned*)((char*)w3l + byt) = pk2(blo(c0), blo(c1));
        }
    }

    // ---- per-lane W1 rows for this lane's B-frag k-slots ----
    float w1v[2][8][3];
#pragma unroll
    for (int s = 0; s < 2; ++s)
#pragma unroll
        for (int j = 0; j < 8; ++j) {
            const int k = s * 32 + lg * 8 + j;
#pragma unroll
            for (int c = 0; c < 3; ++c) w1v[s][j][c] = w1[k * 3 + c];
        }

    // ---- prefetch all 4 groups' gathers (col = lane&31 owns one column) ----
    const int col = lane & 31;
    float gxa[4], gya[4], gza[4];
#pragma unroll
    for (int g = 0; g < 4; ++g) {
        const int n = nbase + g * 8 + wave * 2 + (col >> 4);
        const int j = knn_idx[((size_t)bb * NPTS + n) * KK + (col & 15)];
        gxa[g] = xb[j * 3 + 0] - xb[n * 3 + 0];
        gya[g] = xb[j * 3 + 1] - xb[n * 3 + 1];
        gza[g] = xb[j * 3 + 2] - xb[n * 3 + 2];
    }
    __syncthreads();   // weights staged

    unsigned short* const cbH = cbh[wave];
    unsigned short* const cbL = cbl[wave];

#pragma unroll
    for (int g = 0; g < 4; ++g) {
        // ---- layer 1 in VALU -> layer-2 B-frags (h1 split hi/lo) ----
        bf16x8 b1h[2][2], b1l[2][2];               // [s][t]
#pragma unroll
        for (int t = 0; t < 2; ++t) {
            const int src = t * 16 + lq;
            const float sgx = __shfl(gxa[g], src);
            const float sgy = __shfl(gya[g], src);
            const float sgz = __shfl(gza[g], src);
#pragma unroll
            for (int s = 0; s < 2; ++s) {
                bf16x8 hh, ll;
#pragma unroll
                for (int j = 0; j < 8; ++j) {
                    float v = fmaf(w1v[s][j][2], sgz,
                              fmaf(w1v[s][j][1], sgy, w1v[s][j][0] * sgx));
                    v = fmaxf(v, 0.f);
                    hh[j] = (short)bhi(v);
                    ll[j] = (short)blo(v);
                }
                b1h[s][t] = hh; b1l[s][t] = ll;
            }
        }

        // ---- layer 2: acc[m][t] = W2 . h1 (split-bf16, 48 MFMA) ----
        f32x4 acc[4][2];
#pragma unroll
        for (int m = 0; m < 4; ++m)
#pragma unroll
            for (int t = 0; t < 2; ++t) acc[m][t] = (f32x4){0.f, 0.f, 0.f, 0.f};
#pragma unroll
        for (int m = 0; m < 4; ++m) {
            const int r = m * 16 + lq;
#pragma unroll
            for (int s = 0; s < 2; ++s) {
                const int byt = r * 128 + (((s * 4 + lg) ^ (r & 7)) << 4);
                const bf16x8 ah = *(const bf16x8*)((const char*)w2h + byt);
                const bf16x8 al = *(const bf16x8*)((const char*)w2l + byt);
#pragma unroll
                for (int t = 0; t < 2; ++t) {
                    acc[m][t] = __builtin_amdgcn_mfma_f32_16x16x32_bf16(ah, b1h[s][t], acc[m][t], 0, 0, 0);
                    acc[m][t] = __builtin_amdgcn_mfma_f32_16x16x32_bf16(ah, b1l[s][t], acc[m][t], 0, 0, 0);
                    acc[m][t] = __builtin_amdgcn_mfma_f32_16x16x32_bf16(al, b1h[s][t], acc[m][t], 0, 0, 0);
                }
            }
        }

        // ---- relu(h2) split/pack -> per-wave colbuf [col][k] ----
#pragma unroll
        for (int m = 0; m < 4; ++m)
#pragma unroll
            for (int t = 0; t < 2; ++t) {
                f32x4 v = acc[m][t];
#pragma unroll
                for (int e = 0; e < 4; ++e) v[e] = fmaxf(v[e], 0.f);
                const int co = t * 16 + lq;
                const int k0 = m * 16 + lg * 4;
                const int byt = co * 128 + (((k0 >> 3) ^ (co & 7)) << 4) + (k0 & 7) * 2;
                uint2 hw, lw;
                hw.x = pk2(bhi(v[0]), bhi(v[1])); hw.y = pk2(bhi(v[2]), bhi(v[3]));
                lw.x = pk2(blo(v[0]), blo(v[1])); lw.y = pk2(blo(v[2]), blo(v[3]));
                *(uint2*)((char*)cbH + byt) = hw;
                *(uint2*)((char*)cbL + byt) = lw;
            }

        // ---- layer 3 transposed: D[nb][c3] = h2^T . w3-col (48 MFMA) ----
        bf16x8 xh[2][2], xl[2][2];                 // h2 A-frags [s][t]
#pragma unroll
        for (int s = 0; s < 2; ++s)
#pragma unroll
            for (int t = 0; t < 2; ++t) {
                const int co = t * 16 + lq;
                const int byt = co * 128 + (((s * 4 + lg) ^ (co & 7)) << 4);
                xh[s][t] = *(const bf16x8*)((const char*)cbH + byt);
                xl[s][t] = *(const bf16x8*)((const char*)cbL + byt);
            }
        f32x4 acc3[4][2];
#pragma unroll
        for (int mb = 0; mb < 4; ++mb)
#pragma unroll
            for (int t = 0; t < 2; ++t) acc3[mb][t] = (f32x4){0.f, 0.f, 0.f, 0.f};
#pragma unroll
        for (int mb = 0; mb < 4; ++mb) {
            const int r = mb * 16 + lq;
#pragma unroll
            for (int s = 0; s < 2; ++s) {
                const int byt = r * 128 + (((s * 4 + lg) ^ (r & 7)) << 4);
                const bf16x8 wh = *(const bf16x8*)((const char*)w3h + byt);
                const bf16x8 wl = *(const bf16x8*)((const char*)w3l + byt);
#pragma unroll
                for (int t = 0; t < 2; ++t) {
                    acc3[mb][t] = __builtin_amdgcn_mfma_f32_16x16x32_bf16(xh[s][t], wh, acc3[mb][t], 0, 0, 0);
                    acc3[mb][t] = __builtin_amdgcn_mfma_f32_16x16x32_bf16(xh[s][t], wl, acc3[mb][t], 0, 0, 0);
                    acc3[mb][t] = __builtin_amdgcn_mfma_f32_16x16x32_bf16(xl[s][t], wh, acc3[mb][t], 0, 0, 0);
                }
            }
        }

        // ---- max over neighbors (rows): 3 v_max + 2 shfl ----
#pragma unroll
        for (int mb = 0; mb < 4; ++mb)
#pragma unroll
            for (int t = 0; t < 2; ++t) {
                float v = fmaxf(fmaxf(acc3[mb][t][0], acc3[mb][t][1]),
                                fmaxf(acc3[mb][t][2], acc3[mb][t][3]));
                v = fmaxf(v, __shfl_xor(v, 16));
                v = fmaxf(v, __shfl_xor(v, 32));
                if (lg == 0) obuf[mb * 16 + lq][g * 8 + wave * 2 + t] = v;
            }
    }
    __syncthreads();

    // ---- coalesced store: 64 rows x 32 pts, 32B per thread ----
    {
        const int c = tid >> 2, seg = tid & 3;
        const float4 v0 = *(const float4*)&obuf[c][seg * 8];
        const float4 v1 = *(const float4*)&obuf[c][seg * 8 + 4];
        float* op = &out[((size_t)(bb * CH + c)) * NPTS + nbase + seg * 8];
        *(float4*)op = v0;
        *(float4*)(op + 4) = v1;
    }
}

extern "C" void kernel_launch(void* const* d_in, const int* in_sizes, int n_in,
                              void* d_out, int out_size, void* d_ws, size_t ws_size,
                              hipStream_t stream) {
    (void)in_sizes; (void)n_in; (void)out_size; (void)ws_size;
    const float* xyz = (const float*)d_in[0];
    const float* w1  = (const float*)d_in[1];
    const float* w2  = (const float*)d_in[2];
    const float* w3  = (const float*)d_in[3];
    int*   knn = (int*)d_ws;                 // BATCH*NPTS*KK ints = 1 MiB
    float* out = (float*)d_out;

    knn_kernel<<<BATCH * NPTS / 16, 512, 0, stream>>>(xyz, knn);
    mlp_kernel<<<BATCH * NPTS / 32, 256, 0, stream>>>(xyz, knn, w1, w2, w3, out);
}